// Round 2
// baseline (275.272 us; speedup 1.0000x reference)
//
#include <hip/hip_runtime.h>
#include <math.h>

#define INV_TAU   20.0f
#define LOGN      6.931471805599453f   // log(1024)
#define B1        0.9f
#define B2        0.999f
#define EPS_ADAM  1e-8f

constexpr int BATCH = 8;
constexpr int N = 1024;
constexpr int M = 1024;
constexpr int NCHUNK = 32;            // row chunks for the column pass
constexpr int ROWS_PER_CHUNK = N / NCHUNK;  // 32

// ---------- helpers ----------
__device__ inline float wave_max(float x) {
#pragma unroll
  for (int off = 1; off < 64; off <<= 1) x = fmaxf(x, __shfl_xor(x, off));
  return x;
}
__device__ inline float wave_sum(float x) {
#pragma unroll
  for (int off = 1; off < 64; off <<= 1) x += __shfl_xor(x, off);
  return x;
}

// ---------- zero the Adam/scaling state (ws is poisoned 0xAA every call) ----------
__global__ __launch_bounds__(256) void k_init(float* __restrict__ ws) {
  int i = blockIdx.x * 256 + threadIdx.x;   // 192*256 = 49152 = 6*8192 floats
  ws[i] = 0.0f;
}

// ---------- row LSE over M + Adam update of u  (one wave per row) ----------
__global__ __launch_bounds__(256) void k_row_u(
    const float* __restrict__ la, const float* __restrict__ v,
    float* __restrict__ u, float* __restrict__ mu, float* __restrict__ vu,
    float bc1, float bc2)
{
  int gw   = (blockIdx.x << 2) + (threadIdx.x >> 6);  // global wave = row id (0..8191)
  int lane = threadIdx.x & 63;
  int b = gw >> 10;
  const float4* rowp = (const float4*)(la + (size_t)gw * M);
  const float4* vp   = (const float4*)(v + b * M);

  float x[16];
  float m = -INFINITY;
#pragma unroll
  for (int t = 0; t < 4; ++t) {
    float4 k4 = rowp[lane + 64 * t];
    float4 v4 = vp[lane + 64 * t];
    x[4*t+0] = fmaf(k4.x, INV_TAU, v4.x);
    x[4*t+1] = fmaf(k4.y, INV_TAU, v4.y);
    x[4*t+2] = fmaf(k4.z, INV_TAU, v4.z);
    x[4*t+3] = fmaf(k4.w, INV_TAU, v4.w);
    m = fmaxf(m, fmaxf(fmaxf(x[4*t+0], x[4*t+1]), fmaxf(x[4*t+2], x[4*t+3])));
  }
  m = wave_max(m);
  float s = 0.0f;
#pragma unroll
  for (int t = 0; t < 16; ++t) s += __expf(x[t] - m);
  s = wave_sum(s);

  if (lane == 0) {
    float lse = m + __logf(s);
    float g   = (-LOGN - lse) - u[gw];
    float mn  = B1 * mu[gw] + (1.0f - B1) * g;
    float vn  = B2 * vu[gw] + (1.0f - B2) * g * g;
    mu[gw] = mn;
    vu[gw] = vn;
    u[gw]  = u[gw] + (mn / bc1) / (sqrtf(vn / bc2) + EPS_ADAM);
  }
}

// ---------- column-LSE partials (online LSE over a 32-row chunk) ----------
__global__ __launch_bounds__(256) void k_col_partial(
    const float* __restrict__ la, const float* __restrict__ u,
    float* __restrict__ pm, float* __restrict__ ps)
{
  int b  = blockIdx.x >> 5;          // batch
  int cn = blockIdx.x & 31;          // row chunk
  int tid = threadIdx.x;
  int i0 = cn * ROWS_PER_CHUNK;

  __shared__ float su[ROWS_PER_CHUNK];
  if (tid < ROWS_PER_CHUNK) su[tid] = u[b * N + i0 + tid];
  __syncthreads();

  const float4* base = (const float4*)(la + (size_t)(b * N + i0) * M);
  float4 m = make_float4(-INFINITY, -INFINITY, -INFINITY, -INFINITY);
  float4 s = make_float4(0.f, 0.f, 0.f, 0.f);

#pragma unroll 4
  for (int i = 0; i < ROWS_PER_CHUNK; ++i) {
    float uu = su[i];
    float4 k4 = base[i * 256 + tid];
    float x, nm;
    x = fmaf(k4.x, INV_TAU, uu); nm = fmaxf(m.x, x);
    s.x = s.x * __expf(m.x - nm) + __expf(x - nm); m.x = nm;
    x = fmaf(k4.y, INV_TAU, uu); nm = fmaxf(m.y, x);
    s.y = s.y * __expf(m.y - nm) + __expf(x - nm); m.y = nm;
    x = fmaf(k4.z, INV_TAU, uu); nm = fmaxf(m.z, x);
    s.z = s.z * __expf(m.z - nm) + __expf(x - nm); m.z = nm;
    x = fmaf(k4.w, INV_TAU, uu); nm = fmaxf(m.w, x);
    s.w = s.w * __expf(m.w - nm) + __expf(x - nm); m.w = nm;
  }

  int off = cn * (BATCH * M) + b * M;      // [chunk][b][j]
  ((float4*)(pm + off))[tid] = m;
  ((float4*)(ps + off))[tid] = s;
}

// ---------- combine partials + Adam update of v ----------
__global__ __launch_bounds__(256) void k_combine_v(
    const float* __restrict__ pm, const float* __restrict__ ps,
    float* __restrict__ v, float* __restrict__ mv, float* __restrict__ vv,
    float bc1, float bc2)
{
  int c = blockIdx.x * 256 + threadIdx.x;   // 0..8191 = b*M + j
  float Mx = -INFINITY, S = 0.0f;
#pragma unroll
  for (int cn = 0; cn < NCHUNK; ++cn) {
    float m = pm[cn * (BATCH * M) + c];
    float s = ps[cn * (BATCH * M) + c];
    float nM = fmaxf(Mx, m);
    S = S * __expf(Mx - nM) + s * __expf(m - nM);
    Mx = nM;
  }
  float lse = Mx + __logf(S);
  float g  = (-LOGN - lse) - v[c];
  float mn = B1 * mv[c] + (1.0f - B1) * g;
  float vn = B2 * vv[c] + (1.0f - B2) * g * g;
  mv[c] = mn;
  vv[c] = vn;
  v[c]  = v[c] + (mn / bc1) / (sqrtf(vn / bc2) + EPS_ADAM);
}

// ---------- final transport plan ----------
__global__ __launch_bounds__(256) void k_plan(
    const float* __restrict__ la, const float* __restrict__ u,
    const float* __restrict__ v, float* __restrict__ out)
{
  size_t idx = (size_t)blockIdx.x * 256 + threadIdx.x;  // float4 index, 2M total
  int row = (int)(idx >> 8);          // global row (b*N + i)
  int b   = row >> 10;
  int jc  = (int)(idx & 255);
  float ur  = u[row];
  float4 v4 = ((const float4*)(v + b * M))[jc];
  float4 k4 = ((const float4*)la)[idx];
  float4 o;
  o.x = __expf(fmaf(k4.x, INV_TAU, ur + v4.x));
  o.y = __expf(fmaf(k4.y, INV_TAU, ur + v4.y));
  o.z = __expf(fmaf(k4.z, INV_TAU, ur + v4.z));
  o.w = __expf(fmaf(k4.w, INV_TAU, ur + v4.w));
  ((float4*)out)[idx] = o;
}

extern "C" void kernel_launch(void* const* d_in, const int* in_sizes, int n_in,
                              void* d_out, int out_size, void* d_ws, size_t ws_size,
                              hipStream_t stream) {
  const float* la = (const float*)d_in[0];
  float* out = (float*)d_out;
  float* ws  = (float*)d_ws;

  float* u  = ws;
  float* v  = ws + 8192;
  float* mu = ws + 16384;
  float* vu = ws + 24576;
  float* mv = ws + 32768;
  float* vv = ws + 40960;
  float* pm = ws + 49152;                 // [32][8][1024]
  float* ps = pm + NCHUNK * BATCH * M;    // [32][8][1024]

  k_init<<<192, 256, 0, stream>>>(ws);    // zero u,v,mu,vu,mv,vv

  for (int it = 0; it < 10; ++it) {
    float t = (float)(it + 1);
    float bc1 = 1.0f - powf(B1, t);
    float bc2 = 1.0f - powf(B2, t);
    k_row_u<<<(BATCH * N) / 4, 256, 0, stream>>>(la, v, u, mu, vu, bc1, bc2);
    k_col_partial<<<BATCH * NCHUNK, 256, 0, stream>>>(la, u, pm, ps);
    k_combine_v<<<(BATCH * M) / 256, 256, 0, stream>>>(pm, ps, v, mv, vv, bc1, bc2);
  }
  k_plan<<<(BATCH * N * M) / 4 / 256, 256, 0, stream>>>(la, u, v, out);
}